// Round 9
// baseline (1670.652 us; speedup 1.0000x reference)
//
#include <hip/hip_runtime.h>

// Fused Conv1d(k=3,pad=1) + BN(inference) + 4-step LIF + residual.
// x: (L=2048, TB=128, D=128) f32. conv_w: (D,D,3). out: (L,TB,D) f32.
//
// R11: lane mapping inverted vs R7. Lanes = 64 l-positions; each wave owns a
// 16-o group (2 o-halves x 4 waves -> grid 2048 blocks). x lives in LDS
// transposed [c4][pos]: 3 conflict-free per-lane ds_read_b128 per channel
// group feed 192 FMAs. Weights are WAVE-UNIFORM broadcast global loads from
// a pre-arranged wt (no ws LDS, no per-it barriers: 128 -> 16 barriers/blk;
// waves drift freely). Epilogue transposes spikes through LDS for coalesced
// float4 stores. Per-(o,l) FMA chain bit-identical to R7 (absmax 0.0).

constexpr int L   = 2048;
constexpr int NTB = 128;
constexpr int D   = 128;
constexpr int T   = 4;
constexpr int LT  = 64;        // l per block (= lanes)
constexpr int NP  = LT + 2;    // 66 staged positions

// wt[((g*128 + o)*3 + r)*4 + e] = w[o*384 + (g*4+e)*3 + r]
// float4 r of (g,o) = [k=r, di=0..3] -> pairs with xa/xb/xc.{x,y,z,w}
__global__ void prep_w(const float* __restrict__ w, float* __restrict__ wt) {
    const int i = blockIdx.x * 256 + threadIdx.x;   // over 32*128*12 floats
    if (i >= 32 * 128 * 12) return;
    const int e  = i & 3;
    const int f4 = i >> 2;
    const int r  = f4 % 3;
    const int og = f4 / 3;
    const int o  = og & 127;
    const int g  = og >> 7;
    wt[i] = w[o * 384 + (g * 4 + e) * 3 + r];
}

__global__ __launch_bounds__(256, 4)
void snn_conv_lif(const float* __restrict__ x, const float* __restrict__ wt,
                  const float* __restrict__ gamma, const float* __restrict__ beta,
                  const float* __restrict__ mean, const float* __restrict__ var,
                  float* __restrict__ out) {
    __shared__ float4 buf[32 * NP];   // 33792 B. conv: xs[c4][pos]; epi: sp[l][17]

    const int tid  = threadIdx.x;
    const int lane = tid & 63;
    const int wid  = tid >> 6;
    const int b    = blockIdx.x & 31;
    const int lt   = (blockIdx.x >> 5) & 31;
    const int oh   = blockIdx.x >> 10;         // o-half 0/1
    const int l0   = lt * LT;
    const int c4b  = oh * 16 + wid * 4;        // this thread's channel-group base
    const int obase = c4b * 4;                 // first o of its 16

    const float4* wt4 = (const float4*)wt;
    const float4* x4  = (const float4*)x;

    float vm[16];
    #pragma unroll
    for (int i = 0; i < 16; ++i) vm[i] = 0.f;

    #pragma unroll 1
    for (int t = 0; t < T; ++t) {
        const int n = t * 32 + b;
        __syncthreads();               // prior epilogue LDS readers done
        // ---- stage x -> buf[c4][pos] (global-coalesced reads) ----
        #pragma unroll
        for (int rep = 0; rep < 9; ++rep) {
            const int idx = tid + rep * 256;
            if (idx < NP * 32) {
                const int c4 = idx & 31, pos = idx >> 5;
                const int ll = l0 - 1 + pos;
                float4 val = make_float4(0.f, 0.f, 0.f, 0.f);
                if (ll >= 0 && ll < L) val = x4[(ll * NTB + n) * 32 + c4];
                buf[c4 * NP + pos] = val;
            }
        }
        __syncthreads();

        float acc[16];
        #pragma unroll
        for (int i = 0; i < 16; ++i) acc[i] = 0.f;

        // ---- conv: 32 channel-groups, NO barriers, waves drift freely ----
        #pragma unroll 2
        for (int g = 0; g < 32; ++g) {
            const float4* xc = &buf[g * NP + lane];
            const float4 xa  = xc[0];      // x[l-1][4g..]
            const float4 xb  = xc[1];      // x[l  ][4g..]
            const float4 xcv = xc[2];      // x[l+1][4g..]
            const float4* wp = wt4 + (g * 128 + obase) * 3;   // wave-uniform
            #pragma unroll
            for (int op = 0; op < 16; ++op) {
                const float4 W0 = wp[op * 3 + 0];
                const float4 W1 = wp[op * 3 + 1];
                const float4 W2 = wp[op * 3 + 2];
                float s = acc[op];
                s = fmaf(xa.x,  W0.x, s);  // k=0, i+0
                s = fmaf(xa.y,  W0.y, s);  // k=0, i+1
                s = fmaf(xa.z,  W0.z, s);  // k=0, i+2
                s = fmaf(xa.w,  W0.w, s);  // k=0, i+3
                s = fmaf(xb.x,  W1.x, s);  // k=1, i+0
                s = fmaf(xb.y,  W1.y, s);  // k=1, i+1
                s = fmaf(xb.z,  W1.z, s);  // k=1, i+2
                s = fmaf(xb.w,  W1.w, s);  // k=1, i+3
                s = fmaf(xcv.x, W2.x, s);  // k=2, i+0
                s = fmaf(xcv.y, W2.y, s);  // k=2, i+1
                s = fmaf(xcv.z, W2.z, s);  // k=2, i+2
                s = fmaf(xcv.w, W2.w, s);  // k=2, i+3
                acc[op] = s;
            }
        }

        // ---- BN + LIF + residual (thread = one l, 16 o's) ----
        float4 ov[4];
        #pragma unroll
        for (int r = 0; r < 4; ++r) {
            const float4 res = buf[(c4b + r) * NP + lane + 1];
            const float4 g4  = ((const float4*)gamma)[c4b + r];
            const float4 b4  = ((const float4*)beta )[c4b + r];
            const float4 m4  = ((const float4*)mean )[c4b + r];
            const float4 va4 = ((const float4*)var  )[c4b + r];
            const float re[4] = {res.x, res.y, res.z, res.w};
            const float gg[4] = {g4.x, g4.y, g4.z, g4.w};
            const float bb[4] = {b4.x, b4.y, b4.z, b4.w};
            const float mm[4] = {m4.x, m4.y, m4.z, m4.w};
            const float vv[4] = {va4.x, va4.y, va4.z, va4.w};
            float o4[4];
            #pragma unroll
            for (int e = 0; e < 4; ++e) {
                const float sc = gg[e] / sqrtf(vv[e] + 1e-5f);
                const float bi = bb[e] - mm[e] * sc;
                const float y  = fmaf(acc[r * 4 + e], sc, bi);
                const float h  = 0.5f * (vm[r * 4 + e] + y);   // tau=2
                const bool fire = (h >= 1.0f);
                vm[r * 4 + e] = fire ? 0.0f : h;               // hard reset
                o4[e] = re[e] + (fire ? 1.0f : 0.0f);
            }
            ov[r] = make_float4(o4[0], o4[1], o4[2], o4[3]);
        }

        // ---- transpose spikes through LDS, then coalesced stores ----
        __syncthreads();   // all xs reads (conv + residual) done
        #pragma unroll
        for (int r = 0; r < 4; ++r)
            buf[lane * 17 + wid * 4 + r] = ov[r];   // sp[l][c], pad 17
        __syncthreads();
        #pragma unroll
        for (int rep = 0; rep < 4; ++rep) {
            const int idx = tid + rep * 256;
            const int c   = idx & 15;
            const int lr  = idx >> 4;
            ((float4*)out)[((l0 + lr) * NTB + n) * 32 + oh * 16 + c] =
                buf[lr * 17 + c];
        }
    }
}

extern "C" void kernel_launch(void* const* d_in, const int* in_sizes, int n_in,
                              void* d_out, int out_size, void* d_ws, size_t ws_size,
                              hipStream_t stream) {
    const float* x     = (const float*)d_in[0];
    const float* w     = (const float*)d_in[1];
    const float* gamma = (const float*)d_in[2];
    const float* beta  = (const float*)d_in[3];
    const float* mean  = (const float*)d_in[4];
    const float* var   = (const float*)d_in[5];
    float* out = (float*)d_out;
    float* wt  = (float*)d_ws;    // 196608 B workspace

    prep_w<<<dim3(192), dim3(256), 0, stream>>>(w, wt);

    dim3 grid(2 * 32 * 32);   // o-half x 32 l-tiles x 32 b = 2048 blocks
    dim3 block(256);
    snn_conv_lif<<<grid, block, 0, stream>>>(x, wt, gamma, beta, mean, var, out);
}